// Round 1
// baseline (648.455 us; speedup 1.0000x reference)
//
#include <hip/hip_runtime.h>
#include <hip/hip_bf16.h>
#include <cstdint>
#include <cstddef>

using u16 = unsigned short;
using u32 = unsigned int;
using f32x4 = __attribute__((ext_vector_type(4))) float;
using bf16x8 = __attribute__((ext_vector_type(8))) short;

#define NB   16        // batch
#define NSEQ 3136      // 56*56
#define NH   8
#define HD   64
#define CDIM 512
#define CQKV 1536

static __device__ __forceinline__ u16 f2bf(float f) {
  u32 u = __builtin_bit_cast(u32, f);
  u = (u + 0x7FFFu + ((u >> 16) & 1u)) >> 16;
  return (u16)u;
}
static __device__ __forceinline__ float bf2f(u16 h) {
  u32 u = ((u32)h) << 16;
  return __builtin_bit_cast(float, u);
}
static __device__ __forceinline__ void async16(const void* g, void* l) {
  __builtin_amdgcn_global_load_lds((const __attribute__((address_space(1))) u32*)g,
                                   (__attribute__((address_space(3))) u32*)l, 16, 0, 0);
}

// ---------------- fp32 -> bf16 convert (weights) ----------------
__global__ __launch_bounds__(256) void cvt_kernel(const float* __restrict__ in,
                                                  u16* __restrict__ out, int n4) {
  int i = (int)(blockIdx.x * 256 + threadIdx.x);
  if (i >= n4) return;
  f32x4 v = *(const f32x4*)(in + (size_t)i * 4);
  uint2 uu;
  uu.x = (u32)f2bf(v[0]) | ((u32)f2bf(v[1]) << 16);
  uu.y = (u32)f2bf(v[2]) | ((u32)f2bf(v[3]) << 16);
  *(uint2*)(out + (size_t)i * 4) = uu;
}

// ---------------- bf16 MFMA GEMM: C[m,n] = sum_k A[m,k] * B[n,k] ----------------
// 128x128 tile, BK=64, 4 waves (2x2), 16x16x32 MFMA, m97-style 2-barrier loop.
template<bool A_FP32, bool OUT_FP32>
__global__ __launch_bounds__(256) void gemm_bt(
    const void* __restrict__ Ap, const u16* __restrict__ Bp, void* __restrict__ Cp,
    const float* __restrict__ bias, int M, int N, int K, int lda, int ldb, int ldc, int nbn)
{
  __shared__ u16 As[128 * 64];
  __shared__ u16 Bs[128 * 64];
  int nwg = (int)gridDim.x;
  int bid = (int)blockIdx.x;
  int wg = (bid & 7) * (nwg >> 3) + (bid >> 3);   // XCD swizzle (nwg % 8 == 0)
  int bm = wg / nbn, bn = wg - bm * nbn;
  int m0 = bm * 128, n0 = bn * 128;
  int t = (int)threadIdx.x;
  int lane = t & 63, w = t >> 6;
  int wm = w >> 1, wn = w & 1;
  f32x4 acc[4][4] = {};

  for (int k0 = 0; k0 < K; k0 += 64) {
    if constexpr (A_FP32) {
      const float* A = (const float*)Ap;
      #pragma unroll
      for (int i = 0; i < 8; ++i) {
        int e = i * 1024 + t * 4;
        int row = e >> 6, col = e & 63;
        f32x4 v = *(const f32x4*)(A + (size_t)(m0 + row) * lda + k0 + col);
        uint2 uu;
        uu.x = (u32)f2bf(v[0]) | ((u32)f2bf(v[1]) << 16);
        uu.y = (u32)f2bf(v[2]) | ((u32)f2bf(v[3]) << 16);
        *(uint2*)&As[row * 64 + col] = uu;
      }
    } else {
      const u16* A = (const u16*)Ap;
      #pragma unroll
      for (int i = 0; i < 4; ++i) {
        int chunk = w * 4 + i;
        int row = chunk * 8 + (lane >> 3);
        int col = (lane & 7) * 8;
        async16(A + (size_t)(m0 + row) * lda + k0 + col, &As[chunk * 512]);
      }
    }
    #pragma unroll
    for (int i = 0; i < 4; ++i) {
      int chunk = w * 4 + i;
      int row = chunk * 8 + (lane >> 3);
      int col = (lane & 7) * 8;
      async16(Bp + (size_t)(n0 + row) * ldb + k0 + col, &Bs[chunk * 512]);
    }
    __syncthreads();
    #pragma unroll
    for (int kk = 0; kk < 2; ++kk) {
      int lr = lane & 15;
      int lk = kk * 32 + (lane >> 4) * 8;
      bf16x8 af[4], bq[4];
      #pragma unroll
      for (int mi = 0; mi < 4; ++mi)
        af[mi] = *(const bf16x8*)&As[(wm * 64 + mi * 16 + lr) * 64 + lk];
      #pragma unroll
      for (int ni = 0; ni < 4; ++ni)
        bq[ni] = *(const bf16x8*)&Bs[(wn * 64 + ni * 16 + lr) * 64 + lk];
      #pragma unroll
      for (int mi = 0; mi < 4; ++mi)
        #pragma unroll
        for (int ni = 0; ni < 4; ++ni)
          acc[mi][ni] = __builtin_amdgcn_mfma_f32_16x16x32_bf16(af[mi], bq[ni], acc[mi][ni], 0, 0, 0);
    }
    __syncthreads();
  }
  int lr = lane & 15, lg = lane >> 4;
  #pragma unroll
  for (int mi = 0; mi < 4; ++mi) {
    #pragma unroll
    for (int ni = 0; ni < 4; ++ni) {
      int gcol = n0 + wn * 64 + ni * 16 + lr;
      #pragma unroll
      for (int r = 0; r < 4; ++r) {
        int grow = m0 + wm * 64 + mi * 16 + lg * 4 + r;
        if constexpr (OUT_FP32) {
          ((float*)Cp)[(size_t)grow * ldc + gcol] = acc[mi][ni][r] + bias[gcol];
        } else {
          ((u16*)Cp)[(size_t)grow * ldc + gcol] = f2bf(acc[mi][ni][r]);
        }
      }
    }
  }
}

// ---------------- column softmax stats: per (b,h,d) over N ----------------
__global__ __launch_bounds__(256) void colstats_kernel(const u16* __restrict__ qkvb,
                                                       float* __restrict__ maxb,
                                                       float* __restrict__ sumb) {
  int bh = (int)blockIdx.x;            // b*8 + h
  int t = (int)threadIdx.x;
  int d = t & 63, g = t >> 6;
  const u16* base = qkvb + (size_t)(bh >> 3) * NSEQ * CQKV + CDIM + (bh & 7) * HD + d;
  float m = -3.0e38f, s = 0.f;
  for (int n = g; n < NSEQ; n += 4) {
    float v = bf2f(base[(size_t)n * CQKV]);
    if (v <= m) { s += __expf(v - m); }
    else        { s = s * __expf(m - v) + 1.f; m = v; }
  }
  __shared__ float sm[4][64], ss[4][64];
  sm[g][d] = m; ss[g][d] = s;
  __syncthreads();
  if (t < 64) {
    float M = sm[0][d], S = ss[0][d];
    #pragma unroll
    for (int i = 1; i < 4; ++i) {
      float m2 = sm[i][d], s2 = ss[i][d];
      if (m2 <= M) S += s2 * __expf(m2 - M);
      else         { S = S * __expf(M - m2) + s2; M = m2; }
    }
    maxb[bh * 64 + d] = M;
    sumb[bh * 64 + d] = S;
  }
}

// ---------------- kv partials: kv[b,h,dk,dv] = sum_n softmax(k)[n,dk]*v[n,dv] ----------------
__global__ __launch_bounds__(256) void kv_partial_kernel(const u16* __restrict__ qkvb,
    const float* __restrict__ maxb, const float* __restrict__ sumb, float* __restrict__ part) {
  int bid = (int)blockIdx.x;
  int ns = bid & 7, h = (bid >> 3) & 7, b = bid >> 6;
  int t = (int)threadIdx.x;
  __shared__ float ek[56 * 64];
  __shared__ float vv[56 * 64];
  __shared__ float mx[64], ivs[64];
  if (t < 64) {
    mx[t]  = maxb[(b * 8 + h) * 64 + t];
    ivs[t] = 1.0f / sumb[(b * 8 + h) * 64 + t];
  }
  int dv0 = (t & 15) * 4, dk0 = (t >> 4) * 4;
  float acc[4][4] = {};
  int nbase = ns * 392;
  for (int c0 = 0; c0 < 392; c0 += 56) {
    __syncthreads();
    #pragma unroll
    for (int i = 0; i < 14; ++i) {
      int idx = i * 256 + t;
      int row = idx >> 6, col = idx & 63;
      size_t go = (size_t)(b * NSEQ + nbase + c0 + row) * CQKV + h * HD + col;
      float kv_ = bf2f(qkvb[go + CDIM]);
      ek[row * 64 + col] = __expf(kv_ - mx[col]) * ivs[col];
      vv[row * 64 + col] = bf2f(qkvb[go + 2 * CDIM]);
    }
    __syncthreads();
    for (int n = 0; n < 56; ++n) {
      f32x4 ekv = *(const f32x4*)&ek[n * 64 + dk0];
      f32x4 vvv = *(const f32x4*)&vv[n * 64 + dv0];
      #pragma unroll
      for (int i = 0; i < 4; ++i)
        #pragma unroll
        for (int j = 0; j < 4; ++j)
          acc[i][j] += ekv[i] * vvv[j];
    }
  }
  float* dst = part + (size_t)((ns * 16 + b) * 8 + h) * 4096;
  #pragma unroll
  for (int i = 0; i < 4; ++i) {
    f32x4 o;
    #pragma unroll
    for (int j = 0; j < 4; ++j) o[j] = acc[i][j];
    *(f32x4*)&dst[(dk0 + i) * 64 + dv0] = o;
  }
}

__global__ __launch_bounds__(256) void kv_reduce_kernel(const float* __restrict__ part,
                                                        float* __restrict__ kvb) {
  int idx = (int)(blockIdx.x * 256 + threadIdx.x);   // < 16*8*64*64
  float s = 0.f;
  #pragma unroll
  for (int ns = 0; ns < 8; ++ns) s += part[(size_t)ns * 524288 + idx];
  kvb[idx] = s;
}

// ---------------- depthwise conv on v (image layout), writes over dead k region ----------------
template<int R>
__global__ __launch_bounds__(256) void conv_kernel(u16* __restrict__ qkvb,
    const float* __restrict__ w, const float* __restrict__ bias, int hbase, int nh) {
  constexpr int KS = 2 * R + 1;
  constexpr int WT = 14 + 2 * R;
  __shared__ u16 vt[WT * WT * 64];
  int bid = (int)blockIdx.x;
  int hh = bid % nh;
  int tile = (bid / nh) & 15;
  int b = bid / (nh * 16);
  int h = hbase + hh;
  int y0 = (tile >> 2) * 14, x0 = (tile & 3) * 14;
  int t = (int)threadIdx.x;
  for (int idx = t; idx < WT * WT * 8; idx += 256) {
    int pix = idx >> 3, c8 = idx & 7;
    int py = pix / WT, px = pix - py * WT;
    int gy = y0 + py - R, gx = x0 + px - R;
    uint4 val; val.x = 0u; val.y = 0u; val.z = 0u; val.w = 0u;
    if (gy >= 0 && gy < 56 && gx >= 0 && gx < 56)
      val = *(const uint4*)&qkvb[(size_t)(b * NSEQ + gy * 56 + gx) * CQKV + 2 * CDIM + h * HD + c8 * 8];
    *(uint4*)&vt[pix * 64 + c8 * 8] = val;
  }
  __syncthreads();
  int d = t & 63, g = t >> 6;
  int cg = hh * 64 + d;
  float wr[KS * KS];
  #pragma unroll
  for (int i = 0; i < KS * KS; ++i) wr[i] = w[cg * KS * KS + i];
  float bb = bias[cg];
  for (int px = g; px < 14; px += 4) {
    float acc[14];
    #pragma unroll
    for (int i = 0; i < 14; ++i) acc[i] = bb;
    #pragma unroll
    for (int iy = 0; iy < 14 + 2 * R; ++iy) {
      float val[KS];
      #pragma unroll
      for (int dx = 0; dx < KS; ++dx) val[dx] = bf2f(vt[(iy * WT + px + dx) * 64 + d]);
      #pragma unroll
      for (int dy = 0; dy < KS; ++dy) {
        int py = iy - dy;
        if (py >= 0 && py < 14) {
          #pragma unroll
          for (int dx = 0; dx < KS; ++dx) acc[py] += wr[dy * KS + dx] * val[dx];
        }
      }
    }
    #pragma unroll
    for (int py = 0; py < 14; ++py)
      qkvb[(size_t)(b * NSEQ + (y0 + py) * 56 + x0 + px) * CQKV + CDIM + h * HD + d] = f2bf(acc[py]);
  }
}

// ---------------- combine: out_heads = SCALE * q@kv + q*conv_v, in-place over q ----------------
__global__ __launch_bounds__(256) void combine_kernel(u16* __restrict__ qkvb,
                                                      const float* __restrict__ kvb) {
  int bid = (int)blockIdx.x;
  int rt = bid % 49;
  int h = (bid / 49) & 7;
  int b = bid / 392;
  int n0 = rt * 64;
  int t = (int)threadIdx.x;
  __shared__ float kvs[64 * 64];
  __shared__ u16 qs[64 * 72];
  __shared__ u16 cs[64 * 72];
  const float* src = kvb + (size_t)(b * 8 + h) * 4096;
  #pragma unroll
  for (int i = 0; i < 16; ++i) kvs[i * 256 + t] = src[i * 256 + t];
  #pragma unroll
  for (int i = 0; i < 2; ++i) {
    int chunk = i * 256 + t;
    int row = chunk >> 3, c8 = chunk & 7;
    size_t go = (size_t)(b * NSEQ + n0 + row) * CQKV + h * HD + c8 * 8;
    *(uint4*)&qs[row * 72 + c8 * 8] = *(const uint4*)&qkvb[go];
    *(uint4*)&cs[row * 72 + c8 * 8] = *(const uint4*)&qkvb[go + CDIM];
  }
  __syncthreads();
  int dv0 = (t & 15) * 4, r0 = (t >> 4) * 4;
  float facc[4][4] = {};
  for (int dk = 0; dk < 64; ++dk) {
    f32x4 kvrow = *(const f32x4*)&kvs[dk * 64 + dv0];
    float a0 = bf2f(qs[(r0 + 0) * 72 + dk]);
    float a1 = bf2f(qs[(r0 + 1) * 72 + dk]);
    float a2 = bf2f(qs[(r0 + 2) * 72 + dk]);
    float a3 = bf2f(qs[(r0 + 3) * 72 + dk]);
    #pragma unroll
    for (int j = 0; j < 4; ++j) {
      facc[0][j] += a0 * kvrow[j];
      facc[1][j] += a1 * kvrow[j];
      facc[2][j] += a2 * kvrow[j];
      facc[3][j] += a3 * kvrow[j];
    }
  }
  #pragma unroll
  for (int i = 0; i < 4; ++i) {
    int row = r0 + i;
    u16 ov[4];
    #pragma unroll
    for (int j = 0; j < 4; ++j) {
      float qv = bf2f(qs[row * 72 + dv0 + j]);
      float cv = bf2f(cs[row * 72 + dv0 + j]);
      ov[j] = f2bf(0.125f * facc[i][j] + qv * cv);
    }
    uint2 uu;
    uu.x = (u32)ov[0] | ((u32)ov[1] << 16);
    uu.y = (u32)ov[2] | ((u32)ov[3] << 16);
    *(uint2*)&qkvb[(size_t)(b * NSEQ + n0 + row) * CQKV + h * HD + dv0] = uu;
  }
}

// ---------------- launch ----------------
extern "C" void kernel_launch(void* const* d_in, const int* in_sizes, int n_in,
                              void* d_out, int out_size, void* d_ws, size_t ws_size,
                              hipStream_t stream) {
  (void)in_sizes; (void)n_in; (void)out_size; (void)ws_size;
  const float* x      = (const float*)d_in[0];
  // d_in[1]=H, d_in[2]=W (56, hard-coded)
  const float* w_qkv  = (const float*)d_in[3];
  const float* w_proj = (const float*)d_in[4];
  const float* b_proj = (const float*)d_in[5];
  const float* w3 = (const float*)d_in[6];
  const float* b3 = (const float*)d_in[7];
  const float* w5 = (const float*)d_in[8];
  const float* b5 = (const float*)d_in[9];
  const float* w7 = (const float*)d_in[10];
  const float* b7 = (const float*)d_in[11];
  float* out = (float*)d_out;

  char* ws = (char*)d_ws;
  u16* qkvb = (u16*)ws;        ws += (size_t)50176 * 1536 * 2;   // 154.1 MB
  u16* wqb  = (u16*)ws;        ws += (size_t)1536 * 512 * 2;
  u16* wpb  = (u16*)ws;        ws += (size_t)512 * 512 * 2;
  float* maxb = (float*)ws;    ws += (size_t)16 * 512 * 4;
  float* sumb = (float*)ws;    ws += (size_t)16 * 512 * 4;
  float* kvpart = (float*)ws;  ws += (size_t)8 * 16 * 8 * 64 * 64 * 4;  // 16.8 MB
  float* kvb = (float*)ws;     ws += (size_t)16 * 8 * 64 * 64 * 4;      // 2.1 MB

  cvt_kernel<<<768, 256, 0, stream>>>(w_qkv, wqb, 1536 * 512 / 4);
  cvt_kernel<<<256, 256, 0, stream>>>(w_proj, wpb, 512 * 512 / 4);
  // qkv = x @ w_qkv^T  (bf16 MFMA, fp32 A converted in staging)
  gemm_bt<true, false><<<4704, 256, 0, stream>>>(x, wqb, qkvb, nullptr,
                                                 50176, 1536, 512, 512, 512, 1536, 12);
  colstats_kernel<<<128, 256, 0, stream>>>(qkvb, maxb, sumb);
  kv_partial_kernel<<<1024, 256, 0, stream>>>(qkvb, maxb, sumb, kvpart);
  kv_reduce_kernel<<<2048, 256, 0, stream>>>(kvpart, kvb);
  // depthwise convs: write conv_v over dead k region (cols 512:1024)
  conv_kernel<1><<<512, 256, 0, stream>>>(qkvb, w3, b3, 0, 2);
  conv_kernel<2><<<768, 256, 0, stream>>>(qkvb, w5, b5, 2, 3);
  conv_kernel<3><<<768, 256, 0, stream>>>(qkvb, w7, b7, 5, 3);
  // out_heads = SCALE*q@kv + q*conv_v  (in-place over q, cols 0:512)
  combine_kernel<<<6272, 256, 0, stream>>>(qkvb, kvb);
  // out = out_heads @ w_proj^T + b_proj  (fp32 out)
  gemm_bt<false, true><<<1568, 256, 0, stream>>>(qkvb, wpb, out, b_proj,
                                                 50176, 512, 512, 1536, 512, 512, 4);
}

// Round 2
// 436.117 us; speedup vs baseline: 1.4869x; 1.4869x over previous
//
#include <hip/hip_runtime.h>
#include <hip/hip_bf16.h>
#include <cstdint>
#include <cstddef>

using u16 = unsigned short;
using u32 = unsigned int;
using f32x4 = __attribute__((ext_vector_type(4))) float;
using bf16x8 = __attribute__((ext_vector_type(8))) short;

#define NB   16        // batch
#define NSEQ 3136      // 56*56
#define NH   8
#define HD   64
#define CDIM 512
#define CQKV 1536

static __device__ __forceinline__ u16 f2bf(float f) {
  u32 u = __builtin_bit_cast(u32, f);
  u = (u + 0x7FFFu + ((u >> 16) & 1u)) >> 16;
  return (u16)u;
}
static __device__ __forceinline__ float bf2f(u16 h) {
  u32 u = ((u32)h) << 16;
  return __builtin_bit_cast(float, u);
}
static __device__ __forceinline__ void async16(const void* g, void* l) {
  __builtin_amdgcn_global_load_lds((const __attribute__((address_space(1))) u32*)g,
                                   (__attribute__((address_space(3))) u32*)l, 16, 0, 0);
}

// ---------------- fp32 -> bf16 convert (weights) ----------------
__global__ __launch_bounds__(256) void cvt_kernel(const float* __restrict__ in,
                                                  u16* __restrict__ out, int n4) {
  int i = (int)(blockIdx.x * 256 + threadIdx.x);
  if (i >= n4) return;
  f32x4 v = *(const f32x4*)(in + (size_t)i * 4);
  uint2 uu;
  uu.x = (u32)f2bf(v[0]) | ((u32)f2bf(v[1]) << 16);
  uu.y = (u32)f2bf(v[2]) | ((u32)f2bf(v[3]) << 16);
  *(uint2*)(out + (size_t)i * 4) = uu;
}

// ---------------- bf16 MFMA GEMM: C[m,n] = sum_k A[m,k] * B[n,k] ----------------
// 128x128 tile, BK=64, 4 waves (2x2), 16x16x32 MFMA, m97-style 2-barrier loop.
template<bool A_FP32, bool OUT_FP32>
__global__ __launch_bounds__(256) void gemm_bt(
    const void* __restrict__ Ap, const u16* __restrict__ Bp, void* __restrict__ Cp,
    const float* __restrict__ bias, int M, int N, int K, int lda, int ldb, int ldc, int nbn)
{
  __shared__ u16 As[128 * 64];
  __shared__ u16 Bs[128 * 64];
  int nwg = (int)gridDim.x;
  int bid = (int)blockIdx.x;
  int wg = (bid & 7) * (nwg >> 3) + (bid >> 3);   // XCD swizzle (nwg % 8 == 0)
  int bm = wg / nbn, bn = wg - bm * nbn;
  int m0 = bm * 128, n0 = bn * 128;
  int t = (int)threadIdx.x;
  int lane = t & 63, w = t >> 6;
  int wm = w >> 1, wn = w & 1;
  f32x4 acc[4][4] = {};

  for (int k0 = 0; k0 < K; k0 += 64) {
    if constexpr (A_FP32) {
      const float* A = (const float*)Ap;
      #pragma unroll
      for (int i = 0; i < 8; ++i) {
        int e = i * 1024 + t * 4;
        int row = e >> 6, col = e & 63;
        f32x4 v = *(const f32x4*)(A + (size_t)(m0 + row) * lda + k0 + col);
        uint2 uu;
        uu.x = (u32)f2bf(v[0]) | ((u32)f2bf(v[1]) << 16);
        uu.y = (u32)f2bf(v[2]) | ((u32)f2bf(v[3]) << 16);
        *(uint2*)&As[row * 64 + col] = uu;
      }
    } else {
      const u16* A = (const u16*)Ap;
      #pragma unroll
      for (int i = 0; i < 4; ++i) {
        int chunk = w * 4 + i;
        int row = chunk * 8 + (lane >> 3);
        int col = (lane & 7) * 8;
        async16(A + (size_t)(m0 + row) * lda + k0 + col, &As[chunk * 512]);
      }
    }
    #pragma unroll
    for (int i = 0; i < 4; ++i) {
      int chunk = w * 4 + i;
      int row = chunk * 8 + (lane >> 3);
      int col = (lane & 7) * 8;
      async16(Bp + (size_t)(n0 + row) * ldb + k0 + col, &Bs[chunk * 512]);
    }
    __syncthreads();
    #pragma unroll
    for (int kk = 0; kk < 2; ++kk) {
      int lr = lane & 15;
      int lk = kk * 32 + (lane >> 4) * 8;
      bf16x8 af[4], bq[4];
      #pragma unroll
      for (int mi = 0; mi < 4; ++mi)
        af[mi] = *(const bf16x8*)&As[(wm * 64 + mi * 16 + lr) * 64 + lk];
      #pragma unroll
      for (int ni = 0; ni < 4; ++ni)
        bq[ni] = *(const bf16x8*)&Bs[(wn * 64 + ni * 16 + lr) * 64 + lk];
      #pragma unroll
      for (int mi = 0; mi < 4; ++mi)
        #pragma unroll
        for (int ni = 0; ni < 4; ++ni)
          acc[mi][ni] = __builtin_amdgcn_mfma_f32_16x16x32_bf16(af[mi], bq[ni], acc[mi][ni], 0, 0, 0);
    }
    __syncthreads();
  }
  int lr = lane & 15, lg = lane >> 4;
  #pragma unroll
  for (int mi = 0; mi < 4; ++mi) {
    #pragma unroll
    for (int ni = 0; ni < 4; ++ni) {
      int gcol = n0 + wn * 64 + ni * 16 + lr;
      #pragma unroll
      for (int r = 0; r < 4; ++r) {
        int grow = m0 + wm * 64 + mi * 16 + lg * 4 + r;
        if constexpr (OUT_FP32) {
          ((float*)Cp)[(size_t)grow * ldc + gcol] = acc[mi][ni][r] + bias[gcol];
        } else {
          ((u16*)Cp)[(size_t)grow * ldc + gcol] = f2bf(acc[mi][ni][r]);
        }
      }
    }
  }
}

// ---------------- column softmax stats, pass 1: per (b,h,ns) chunk partials ----------------
// Each block: 392 rows of one (b,h). Thread t: d-group = (t&7)*8, row-lane = t>>3.
// Coalesced uint4 loads (16 B/lane). Online max/sum in registers, LDS combine.
__global__ __launch_bounds__(256) void colstats_part_kernel(const u16* __restrict__ qkvb,
                                                            float* __restrict__ pm,
                                                            float* __restrict__ ps) {
  int bid = (int)blockIdx.x;           // b*64 + h*8 + ns
  int ns = bid & 7, h = (bid >> 3) & 7, b = bid >> 6;
  int t = (int)threadIdx.x;
  int d8 = t & 7, rl = t >> 3;
  const u16* base = qkvb + (size_t)b * NSEQ * CQKV + CDIM + h * HD + d8 * 8;
  int nbase = ns * 392;
  float m[8], s[8];
  #pragma unroll
  for (int j = 0; j < 8; ++j) { m[j] = -3.0e38f; s[j] = 0.f; }
  for (int it = 0; it < 13; ++it) {
    int row = it * 32 + rl;
    if (row < 392) {
      uint4 val = *(const uint4*)(base + (size_t)(nbase + row) * CQKV);
      const u16* p = (const u16*)&val;
      #pragma unroll
      for (int j = 0; j < 8; ++j) {
        float v = bf2f(p[j]);
        if (v <= m[j]) { s[j] += __expf(v - m[j]); }
        else           { s[j] = s[j] * __expf(m[j] - v) + 1.f; m[j] = v; }
      }
    }
  }
  __shared__ float sm[256][8], ss[256][8];
  #pragma unroll
  for (int j = 0; j < 8; ++j) { sm[t][j] = m[j]; ss[t][j] = s[j]; }
  __syncthreads();
  if (t < 64) {
    int dd8 = t >> 3, dj = t & 7;
    float M = -3.0e38f, S = 0.f;
    #pragma unroll
    for (int r = 0; r < 32; ++r) {
      float m2 = sm[r * 8 + dd8][dj], s2 = ss[r * 8 + dd8][dj];
      if (m2 <= M) { S += s2 * __expf(m2 - M); }
      else         { S = S * __expf(M - m2) + s2; M = m2; }
    }
    pm[bid * 64 + t] = M;
    ps[bid * 64 + t] = S;
  }
}

// pass 2: combine 8 chunk partials per (b,h,d)
__global__ __launch_bounds__(256) void colstats_reduce_kernel(const float* __restrict__ pm,
                                                              const float* __restrict__ ps,
                                                              float* __restrict__ maxb,
                                                              float* __restrict__ sumb) {
  int idx = (int)(blockIdx.x * 256 + threadIdx.x);   // < 128*64
  int bh = idx >> 6, d = idx & 63;
  float M = -3.0e38f, S = 0.f;
  #pragma unroll
  for (int ns = 0; ns < 8; ++ns) {
    float m2 = pm[((bh << 3) + ns) * 64 + d], s2 = ps[((bh << 3) + ns) * 64 + d];
    if (m2 <= M) { S += s2 * __expf(m2 - M); }
    else         { S = S * __expf(M - m2) + s2; M = m2; }
  }
  maxb[idx] = M;
  sumb[idx] = S;
}

// ---------------- kv partials: kv[b,h,dk,dv] = sum_n softmax(k)[n,dk]*v[n,dv] ----------------
__global__ __launch_bounds__(256) void kv_partial_kernel(const u16* __restrict__ qkvb,
    const float* __restrict__ maxb, const float* __restrict__ sumb, float* __restrict__ part) {
  int bid = (int)blockIdx.x;
  int ns = bid & 7, h = (bid >> 3) & 7, b = bid >> 6;
  int t = (int)threadIdx.x;
  __shared__ float ek[56 * 64];
  __shared__ float vv[56 * 64];
  __shared__ float mx[64], ivs[64];
  if (t < 64) {
    mx[t]  = maxb[(b * 8 + h) * 64 + t];
    ivs[t] = 1.0f / sumb[(b * 8 + h) * 64 + t];
  }
  int dv0 = (t & 15) * 4, dk0 = (t >> 4) * 4;
  float acc[4][4] = {};
  int nbase = ns * 392;
  for (int c0 = 0; c0 < 392; c0 += 56) {
    __syncthreads();
    #pragma unroll
    for (int i = 0; i < 14; ++i) {
      int idx = i * 256 + t;
      int row = idx >> 6, col = idx & 63;
      size_t go = (size_t)(b * NSEQ + nbase + c0 + row) * CQKV + h * HD + col;
      float kv_ = bf2f(qkvb[go + CDIM]);
      ek[row * 64 + col] = __expf(kv_ - mx[col]) * ivs[col];
      vv[row * 64 + col] = bf2f(qkvb[go + 2 * CDIM]);
    }
    __syncthreads();
    for (int n = 0; n < 56; ++n) {
      f32x4 ekv = *(const f32x4*)&ek[n * 64 + dk0];
      f32x4 vvv = *(const f32x4*)&vv[n * 64 + dv0];
      #pragma unroll
      for (int i = 0; i < 4; ++i)
        #pragma unroll
        for (int j = 0; j < 4; ++j)
          acc[i][j] += ekv[i] * vvv[j];
    }
  }
  float* dst = part + (size_t)((ns * 16 + b) * 8 + h) * 4096;
  #pragma unroll
  for (int i = 0; i < 4; ++i) {
    f32x4 o;
    #pragma unroll
    for (int j = 0; j < 4; ++j) o[j] = acc[i][j];
    *(f32x4*)&dst[(dk0 + i) * 64 + dv0] = o;
  }
}

__global__ __launch_bounds__(256) void kv_reduce_kernel(const float* __restrict__ part,
                                                        float* __restrict__ kvb) {
  int idx = (int)(blockIdx.x * 256 + threadIdx.x);   // < 16*8*64*64
  float s = 0.f;
  #pragma unroll
  for (int ns = 0; ns < 8; ++ns) s += part[(size_t)ns * 524288 + idx];
  kvb[idx] = s;
}

// ---------------- depthwise conv on v (image layout), writes over dead k region ----------------
template<int R>
__global__ __launch_bounds__(256) void conv_kernel(u16* __restrict__ qkvb,
    const float* __restrict__ w, const float* __restrict__ bias, int hbase, int nh) {
  constexpr int KS = 2 * R + 1;
  constexpr int WT = 14 + 2 * R;
  __shared__ u16 vt[WT * WT * 64];
  int bid = (int)blockIdx.x;
  int hh = bid % nh;
  int tile = (bid / nh) & 15;
  int b = bid / (nh * 16);
  int h = hbase + hh;
  int y0 = (tile >> 2) * 14, x0 = (tile & 3) * 14;
  int t = (int)threadIdx.x;
  for (int idx = t; idx < WT * WT * 8; idx += 256) {
    int pix = idx >> 3, c8 = idx & 7;
    int py = pix / WT, px = pix - py * WT;
    int gy = y0 + py - R, gx = x0 + px - R;
    uint4 val; val.x = 0u; val.y = 0u; val.z = 0u; val.w = 0u;
    if (gy >= 0 && gy < 56 && gx >= 0 && gx < 56)
      val = *(const uint4*)&qkvb[(size_t)(b * NSEQ + gy * 56 + gx) * CQKV + 2 * CDIM + h * HD + c8 * 8];
    *(uint4*)&vt[pix * 64 + c8 * 8] = val;
  }
  __syncthreads();
  int d = t & 63, g = t >> 6;
  int cg = hh * 64 + d;
  float wr[KS * KS];
  #pragma unroll
  for (int i = 0; i < KS * KS; ++i) wr[i] = w[cg * KS * KS + i];
  float bb = bias[cg];
  for (int px = g; px < 14; px += 4) {
    float acc[14];
    #pragma unroll
    for (int i = 0; i < 14; ++i) acc[i] = bb;
    #pragma unroll
    for (int iy = 0; iy < 14 + 2 * R; ++iy) {
      float val[KS];
      #pragma unroll
      for (int dx = 0; dx < KS; ++dx) val[dx] = bf2f(vt[(iy * WT + px + dx) * 64 + d]);
      #pragma unroll
      for (int dy = 0; dy < KS; ++dy) {
        int py = iy - dy;
        if (py >= 0 && py < 14) {
          #pragma unroll
          for (int dx = 0; dx < KS; ++dx) acc[py] += wr[dy * KS + dx] * val[dx];
        }
      }
    }
    #pragma unroll
    for (int py = 0; py < 14; ++py)
      qkvb[(size_t)(b * NSEQ + (y0 + py) * 56 + x0 + px) * CQKV + CDIM + h * HD + d] = f2bf(acc[py]);
  }
}

// ---------------- combine: out_heads = SCALE * q@kv + q*conv_v, in-place over q ----------------
__global__ __launch_bounds__(256) void combine_kernel(u16* __restrict__ qkvb,
                                                      const float* __restrict__ kvb) {
  int bid = (int)blockIdx.x;
  int rt = bid % 49;
  int h = (bid / 49) & 7;
  int b = bid / 392;
  int n0 = rt * 64;
  int t = (int)threadIdx.x;
  __shared__ float kvs[64 * 64];
  __shared__ u16 qs[64 * 72];
  __shared__ u16 cs[64 * 72];
  const float* src = kvb + (size_t)(b * 8 + h) * 4096;
  #pragma unroll
  for (int i = 0; i < 16; ++i) kvs[i * 256 + t] = src[i * 256 + t];
  #pragma unroll
  for (int i = 0; i < 2; ++i) {
    int chunk = i * 256 + t;
    int row = chunk >> 3, c8 = chunk & 7;
    size_t go = (size_t)(b * NSEQ + n0 + row) * CQKV + h * HD + c8 * 8;
    *(uint4*)&qs[row * 72 + c8 * 8] = *(const uint4*)&qkvb[go];
    *(uint4*)&cs[row * 72 + c8 * 8] = *(const uint4*)&qkvb[go + CDIM];
  }
  __syncthreads();
  int dv0 = (t & 15) * 4, r0 = (t >> 4) * 4;
  float facc[4][4] = {};
  for (int dk = 0; dk < 64; ++dk) {
    f32x4 kvrow = *(const f32x4*)&kvs[dk * 64 + dv0];
    float a0 = bf2f(qs[(r0 + 0) * 72 + dk]);
    float a1 = bf2f(qs[(r0 + 1) * 72 + dk]);
    float a2 = bf2f(qs[(r0 + 2) * 72 + dk]);
    float a3 = bf2f(qs[(r0 + 3) * 72 + dk]);
    #pragma unroll
    for (int j = 0; j < 4; ++j) {
      facc[0][j] += a0 * kvrow[j];
      facc[1][j] += a1 * kvrow[j];
      facc[2][j] += a2 * kvrow[j];
      facc[3][j] += a3 * kvrow[j];
    }
  }
  #pragma unroll
  for (int i = 0; i < 4; ++i) {
    int row = r0 + i;
    u16 ov[4];
    #pragma unroll
    for (int j = 0; j < 4; ++j) {
      float qv = bf2f(qs[row * 72 + dv0 + j]);
      float cv = bf2f(cs[row * 72 + dv0 + j]);
      ov[j] = f2bf(0.125f * facc[i][j] + qv * cv);
    }
    uint2 uu;
    uu.x = (u32)ov[0] | ((u32)ov[1] << 16);
    uu.y = (u32)ov[2] | ((u32)ov[3] << 16);
    *(uint2*)&qkvb[(size_t)(b * NSEQ + n0 + row) * CQKV + h * HD + dv0] = uu;
  }
}

// ---------------- launch ----------------
extern "C" void kernel_launch(void* const* d_in, const int* in_sizes, int n_in,
                              void* d_out, int out_size, void* d_ws, size_t ws_size,
                              hipStream_t stream) {
  (void)in_sizes; (void)n_in; (void)out_size; (void)ws_size;
  const float* x      = (const float*)d_in[0];
  // d_in[1]=H, d_in[2]=W (56, hard-coded)
  const float* w_qkv  = (const float*)d_in[3];
  const float* w_proj = (const float*)d_in[4];
  const float* b_proj = (const float*)d_in[5];
  const float* w3 = (const float*)d_in[6];
  const float* b3 = (const float*)d_in[7];
  const float* w5 = (const float*)d_in[8];
  const float* b5 = (const float*)d_in[9];
  const float* w7 = (const float*)d_in[10];
  const float* b7 = (const float*)d_in[11];
  float* out = (float*)d_out;

  char* ws = (char*)d_ws;
  u16* qkvb = (u16*)ws;        ws += (size_t)50176 * 1536 * 2;   // 154.1 MB
  u16* wqb  = (u16*)ws;        ws += (size_t)1536 * 512 * 2;
  u16* wpb  = (u16*)ws;        ws += (size_t)512 * 512 * 2;
  float* maxb = (float*)ws;    ws += (size_t)16 * 512 * 4;
  float* sumb = (float*)ws;    ws += (size_t)16 * 512 * 4;
  float* kvpart = (float*)ws;  ws += (size_t)8 * 16 * 8 * 64 * 64 * 4;  // 16.8 MB
  float* kvb = (float*)ws;     ws += (size_t)16 * 8 * 64 * 64 * 4;      // 2.1 MB

  // colstats partials reuse kvpart scratch (dead until kv_partial runs)
  float* pm = kvpart;            // 1024*64 floats
  float* ps = kvpart + 65536;    // 1024*64 floats

  cvt_kernel<<<768, 256, 0, stream>>>(w_qkv, wqb, 1536 * 512 / 4);
  cvt_kernel<<<256, 256, 0, stream>>>(w_proj, wpb, 512 * 512 / 4);
  // qkv = x @ w_qkv^T  (bf16 MFMA, fp32 A converted in staging)
  gemm_bt<true, false><<<4704, 256, 0, stream>>>(x, wqb, qkvb, nullptr,
                                                 50176, 1536, 512, 512, 512, 1536, 12);
  colstats_part_kernel<<<1024, 256, 0, stream>>>(qkvb, pm, ps);
  colstats_reduce_kernel<<<32, 256, 0, stream>>>(pm, ps, maxb, sumb);
  kv_partial_kernel<<<1024, 256, 0, stream>>>(qkvb, maxb, sumb, kvpart);
  kv_reduce_kernel<<<2048, 256, 0, stream>>>(kvpart, kvb);
  // depthwise convs: write conv_v over dead k region (cols 512:1024)
  conv_kernel<1><<<512, 256, 0, stream>>>(qkvb, w3, b3, 0, 2);
  conv_kernel<2><<<768, 256, 0, stream>>>(qkvb, w5, b5, 2, 3);
  conv_kernel<3><<<768, 256, 0, stream>>>(qkvb, w7, b7, 5, 3);
  // out_heads = SCALE*q@kv + q*conv_v  (in-place over q, cols 0:512)
  combine_kernel<<<6272, 256, 0, stream>>>(qkvb, kvb);
  // out = out_heads @ w_proj^T + b_proj  (fp32 out)
  gemm_bt<false, true><<<1568, 256, 0, stream>>>(qkvb, wpb, out, b_proj,
                                                 50176, 512, 512, 1536, 512, 512, 4);
}

// Round 3
// 409.775 us; speedup vs baseline: 1.5825x; 1.0643x over previous
//
#include <hip/hip_runtime.h>
#include <hip/hip_bf16.h>
#include <cstdint>
#include <cstddef>

using u16 = unsigned short;
using u32 = unsigned int;
using f32x4 = __attribute__((ext_vector_type(4))) float;
using bf16x8 = __attribute__((ext_vector_type(8))) short;

#define NB   16        // batch
#define NSEQ 3136      // 56*56
#define NH   8
#define HD   64
#define CDIM 512
#define CQKV 1536

static __device__ __forceinline__ u16 f2bf(float f) {
  u32 u = __builtin_bit_cast(u32, f);
  u = (u + 0x7FFFu + ((u >> 16) & 1u)) >> 16;
  return (u16)u;
}
static __device__ __forceinline__ float bf2f(u16 h) {
  u32 u = ((u32)h) << 16;
  return __builtin_bit_cast(float, u);
}
static __device__ __forceinline__ void async16(const void* g, void* l) {
  __builtin_amdgcn_global_load_lds((const __attribute__((address_space(1))) u32*)g,
                                   (__attribute__((address_space(3))) u32*)l, 16, 0, 0);
}

// ---------------- fp32 -> bf16 convert ----------------
__global__ __launch_bounds__(256) void cvt_kernel(const float* __restrict__ in,
                                                  u16* __restrict__ out, int n4) {
  int i = (int)(blockIdx.x * 256 + threadIdx.x);
  if (i >= n4) return;
  f32x4 v = *(const f32x4*)(in + (size_t)i * 4);
  uint2 uu;
  uu.x = (u32)f2bf(v[0]) | ((u32)f2bf(v[1]) << 16);
  uu.y = (u32)f2bf(v[2]) | ((u32)f2bf(v[3]) << 16);
  *(uint2*)(out + (size_t)i * 4) = uu;
}

// ---------------- bf16 MFMA GEMM: C[m,n] = sum_k A[m,k] * B[n,k] ----------------
// 128x128 tile, BK=64, 4 waves (2x2), 16x16x32 MFMA, m97-style 2-barrier loop.
template<bool A_FP32, bool OUT_FP32>
__global__ __launch_bounds__(256) void gemm_bt(
    const void* __restrict__ Ap, const u16* __restrict__ Bp, void* __restrict__ Cp,
    const float* __restrict__ bias, int M, int N, int K, int lda, int ldb, int ldc, int nbn)
{
  __shared__ u16 As[128 * 64];
  __shared__ u16 Bs[128 * 64];
  int nwg = (int)gridDim.x;
  int bid = (int)blockIdx.x;
  int wg = (bid & 7) * (nwg >> 3) + (bid >> 3);   // XCD swizzle (nwg % 8 == 0)
  int bm = wg / nbn, bn = wg - bm * nbn;
  int m0 = bm * 128, n0 = bn * 128;
  int t = (int)threadIdx.x;
  int lane = t & 63, w = t >> 6;
  int wm = w >> 1, wn = w & 1;
  f32x4 acc[4][4] = {};

  for (int k0 = 0; k0 < K; k0 += 64) {
    if constexpr (A_FP32) {
      const float* A = (const float*)Ap;
      #pragma unroll
      for (int i = 0; i < 8; ++i) {
        int e = i * 1024 + t * 4;
        int row = e >> 6, col = e & 63;
        f32x4 v = *(const f32x4*)(A + (size_t)(m0 + row) * lda + k0 + col);
        uint2 uu;
        uu.x = (u32)f2bf(v[0]) | ((u32)f2bf(v[1]) << 16);
        uu.y = (u32)f2bf(v[2]) | ((u32)f2bf(v[3]) << 16);
        *(uint2*)&As[row * 64 + col] = uu;
      }
    } else {
      const u16* A = (const u16*)Ap;
      #pragma unroll
      for (int i = 0; i < 4; ++i) {
        int chunk = w * 4 + i;
        int row = chunk * 8 + (lane >> 3);
        int col = (lane & 7) * 8;
        async16(A + (size_t)(m0 + row) * lda + k0 + col, &As[chunk * 512]);
      }
    }
    #pragma unroll
    for (int i = 0; i < 4; ++i) {
      int chunk = w * 4 + i;
      int row = chunk * 8 + (lane >> 3);
      int col = (lane & 7) * 8;
      async16(Bp + (size_t)(n0 + row) * ldb + k0 + col, &Bs[chunk * 512]);
    }
    __syncthreads();
    #pragma unroll
    for (int kk = 0; kk < 2; ++kk) {
      int lr = lane & 15;
      int lk = kk * 32 + (lane >> 4) * 8;
      bf16x8 af[4], bq[4];
      #pragma unroll
      for (int mi = 0; mi < 4; ++mi)
        af[mi] = *(const bf16x8*)&As[(wm * 64 + mi * 16 + lr) * 64 + lk];
      #pragma unroll
      for (int ni = 0; ni < 4; ++ni)
        bq[ni] = *(const bf16x8*)&Bs[(wn * 64 + ni * 16 + lr) * 64 + lk];
      #pragma unroll
      for (int mi = 0; mi < 4; ++mi)
        #pragma unroll
        for (int ni = 0; ni < 4; ++ni)
          acc[mi][ni] = __builtin_amdgcn_mfma_f32_16x16x32_bf16(af[mi], bq[ni], acc[mi][ni], 0, 0, 0);
    }
    __syncthreads();
  }
  int lr = lane & 15, lg = lane >> 4;
  #pragma unroll
  for (int mi = 0; mi < 4; ++mi) {
    #pragma unroll
    for (int ni = 0; ni < 4; ++ni) {
      int gcol = n0 + wn * 64 + ni * 16 + lr;
      #pragma unroll
      for (int r = 0; r < 4; ++r) {
        int grow = m0 + wm * 64 + mi * 16 + lg * 4 + r;
        if constexpr (OUT_FP32) {
          ((float*)Cp)[(size_t)grow * ldc + gcol] = acc[mi][ni][r] + bias[gcol];
        } else {
          ((u16*)Cp)[(size_t)grow * ldc + gcol] = f2bf(acc[mi][ni][r]);
        }
      }
    }
  }
}

// ---------------- column softmax stats, pass 1: per (b,h,ns) chunk partials ----------------
__global__ __launch_bounds__(256) void colstats_part_kernel(const u16* __restrict__ qkvb,
                                                            float* __restrict__ pm,
                                                            float* __restrict__ ps) {
  int bid = (int)blockIdx.x;           // b*64 + h*8 + ns
  int ns = bid & 7, h = (bid >> 3) & 7, b = bid >> 6;
  int t = (int)threadIdx.x;
  int d8 = t & 7, rl = t >> 3;
  const u16* base = qkvb + (size_t)b * NSEQ * CQKV + CDIM + h * HD + d8 * 8;
  int nbase = ns * 392;
  float m[8], s[8];
  #pragma unroll
  for (int j = 0; j < 8; ++j) { m[j] = -3.0e38f; s[j] = 0.f; }
  for (int it = 0; it < 13; ++it) {
    int row = it * 32 + rl;
    if (row < 392) {
      uint4 val = *(const uint4*)(base + (size_t)(nbase + row) * CQKV);
      const u16* p = (const u16*)&val;
      #pragma unroll
      for (int j = 0; j < 8; ++j) {
        float v = bf2f(p[j]);
        if (v <= m[j]) { s[j] += __expf(v - m[j]); }
        else           { s[j] = s[j] * __expf(m[j] - v) + 1.f; m[j] = v; }
      }
    }
  }
  __shared__ float sm[256][8], ss[256][8];
  #pragma unroll
  for (int j = 0; j < 8; ++j) { sm[t][j] = m[j]; ss[t][j] = s[j]; }
  __syncthreads();
  if (t < 64) {
    int dd8 = t >> 3, dj = t & 7;
    float M = -3.0e38f, S = 0.f;
    #pragma unroll
    for (int r = 0; r < 32; ++r) {
      float m2 = sm[r * 8 + dd8][dj], s2 = ss[r * 8 + dd8][dj];
      if (m2 <= M) { S += s2 * __expf(m2 - M); }
      else         { S = S * __expf(M - m2) + s2; M = m2; }
    }
    pm[bid * 64 + t] = M;
    ps[bid * 64 + t] = S;
  }
}

// pass 2: combine 8 chunk partials per (b,h,d)
__global__ __launch_bounds__(256) void colstats_reduce_kernel(const float* __restrict__ pm,
                                                              const float* __restrict__ ps,
                                                              float* __restrict__ maxb,
                                                              float* __restrict__ sumb) {
  int idx = (int)(blockIdx.x * 256 + threadIdx.x);   // < 128*64
  int bh = idx >> 6, d = idx & 63;
  float M = -3.0e38f, S = 0.f;
  #pragma unroll
  for (int ns = 0; ns < 8; ++ns) {
    float m2 = pm[((bh << 3) + ns) * 64 + d], s2 = ps[((bh << 3) + ns) * 64 + d];
    if (m2 <= M) { S += s2 * __expf(m2 - M); }
    else         { S = S * __expf(M - m2) + s2; M = m2; }
  }
  maxb[idx] = M;
  sumb[idx] = S;
}

// ---------------- kv partials: kv[b,h,dk,dv] = sum_n softmax(k)[n,dk]*v[n,dv] ----------------
__global__ __launch_bounds__(256) void kv_partial_kernel(const u16* __restrict__ qkvb,
    const float* __restrict__ maxb, const float* __restrict__ sumb, float* __restrict__ part) {
  int bid = (int)blockIdx.x;
  int ns = bid & 7, h = (bid >> 3) & 7, b = bid >> 6;
  int t = (int)threadIdx.x;
  __shared__ float ek[56 * 64];
  __shared__ float vv[56 * 64];
  __shared__ float mx[64], ivs[64];
  if (t < 64) {
    mx[t]  = maxb[(b * 8 + h) * 64 + t];
    ivs[t] = 1.0f / sumb[(b * 8 + h) * 64 + t];
  }
  int dv0 = (t & 15) * 4, dk0 = (t >> 4) * 4;
  float acc[4][4] = {};
  int nbase = ns * 392;
  for (int c0 = 0; c0 < 392; c0 += 56) {
    __syncthreads();
    // 56 rows x 64 cols, uint4 (8 bf16) per item: 448 items over 256 threads
    for (int idx = t; idx < 448; idx += 256) {
      int row = idx >> 3, c8 = idx & 7;
      size_t go = (size_t)(b * NSEQ + nbase + c0 + row) * CQKV + h * HD + c8 * 8;
      uint4 kq = *(const uint4*)&qkvb[go + CDIM];
      uint4 vq = *(const uint4*)&qkvb[go + 2 * CDIM];
      const u16* kp = (const u16*)&kq;
      const u16* vp = (const u16*)&vq;
      #pragma unroll
      for (int j = 0; j < 8; ++j) {
        int col = c8 * 8 + j;
        ek[row * 64 + col] = __expf(bf2f(kp[j]) - mx[col]) * ivs[col];
        vv[row * 64 + col] = bf2f(vp[j]);
      }
    }
    __syncthreads();
    for (int n = 0; n < 56; ++n) {
      f32x4 ekv = *(const f32x4*)&ek[n * 64 + dk0];
      f32x4 vvv = *(const f32x4*)&vv[n * 64 + dv0];
      #pragma unroll
      for (int i = 0; i < 4; ++i)
        #pragma unroll
        for (int j = 0; j < 4; ++j)
          acc[i][j] += ekv[i] * vvv[j];
    }
  }
  float* dst = part + (size_t)((ns * 16 + b) * 8 + h) * 4096;
  #pragma unroll
  for (int i = 0; i < 4; ++i) {
    f32x4 o;
    #pragma unroll
    for (int j = 0; j < 4; ++j) o[j] = acc[i][j];
    *(f32x4*)&dst[(dk0 + i) * 64 + dv0] = o;
  }
}

__global__ __launch_bounds__(256) void kv_reduce_kernel(const float* __restrict__ part,
                                                        float* __restrict__ kvb) {
  int idx = (int)(blockIdx.x * 256 + threadIdx.x);   // < 16*8*64*64
  float s = 0.f;
  #pragma unroll
  for (int ns = 0; ns < 8; ++ns) s += part[(size_t)ns * 524288 + idx];
  kvb[idx] = s;
}

// ---------------- depthwise conv on v (image layout), writes over dead k region ----------------
template<int R>
__global__ __launch_bounds__(256) void conv_kernel(u16* __restrict__ qkvb,
    const float* __restrict__ w, const float* __restrict__ bias, int hbase, int nh) {
  constexpr int KS = 2 * R + 1;
  constexpr int WT = 14 + 2 * R;
  __shared__ u16 vt[WT * WT * 64];
  int bid = (int)blockIdx.x;
  int hh = bid % nh;
  int tile = (bid / nh) & 15;
  int b = bid / (nh * 16);
  int h = hbase + hh;
  int y0 = (tile >> 2) * 14, x0 = (tile & 3) * 14;
  int t = (int)threadIdx.x;
  for (int idx = t; idx < WT * WT * 8; idx += 256) {
    int pix = idx >> 3, c8 = idx & 7;
    int py = pix / WT, px = pix - py * WT;
    int gy = y0 + py - R, gx = x0 + px - R;
    uint4 val; val.x = 0u; val.y = 0u; val.z = 0u; val.w = 0u;
    if (gy >= 0 && gy < 56 && gx >= 0 && gx < 56)
      val = *(const uint4*)&qkvb[(size_t)(b * NSEQ + gy * 56 + gx) * CQKV + 2 * CDIM + h * HD + c8 * 8];
    *(uint4*)&vt[pix * 64 + c8 * 8] = val;
  }
  __syncthreads();
  int d = t & 63, g = t >> 6;
  int cg = hh * 64 + d;
  float wr[KS * KS];
  #pragma unroll
  for (int i = 0; i < KS * KS; ++i) wr[i] = w[cg * KS * KS + i];
  float bb = bias[cg];
  for (int px = g; px < 14; px += 4) {
    float acc[14];
    #pragma unroll
    for (int i = 0; i < 14; ++i) acc[i] = bb;
    #pragma unroll
    for (int iy = 0; iy < 14 + 2 * R; ++iy) {
      float val[KS];
      #pragma unroll
      for (int dx = 0; dx < KS; ++dx) val[dx] = bf2f(vt[(iy * WT + px + dx) * 64 + d]);
      #pragma unroll
      for (int dy = 0; dy < KS; ++dy) {
        int py = iy - dy;
        if (py >= 0 && py < 14) {
          #pragma unroll
          for (int dx = 0; dx < KS; ++dx) acc[py] += wr[dy * KS + dx] * val[dx];
        }
      }
    }
    #pragma unroll
    for (int py = 0; py < 14; ++py)
      qkvb[(size_t)(b * NSEQ + (y0 + py) * 56 + x0 + px) * CQKV + CDIM + h * HD + d] = f2bf(acc[py]);
  }
}

// ---------------- combine: out_heads = SCALE * q@kv + q*conv_v, in-place over q ----------------
__global__ __launch_bounds__(256) void combine_kernel(u16* __restrict__ qkvb,
                                                      const float* __restrict__ kvb) {
  int bid = (int)blockIdx.x;
  int rt = bid % 49;
  int h = (bid / 49) & 7;
  int b = bid / 392;
  int n0 = rt * 64;
  int t = (int)threadIdx.x;
  __shared__ float kvs[64 * 64];
  __shared__ u16 qs[64 * 72];
  __shared__ u16 cs[64 * 72];
  const float* src = kvb + (size_t)(b * 8 + h) * 4096;
  #pragma unroll
  for (int i = 0; i < 16; ++i) kvs[i * 256 + t] = src[i * 256 + t];
  #pragma unroll
  for (int i = 0; i < 2; ++i) {
    int chunk = i * 256 + t;
    int row = chunk >> 3, c8 = chunk & 7;
    size_t go = (size_t)(b * NSEQ + n0 + row) * CQKV + h * HD + c8 * 8;
    *(uint4*)&qs[row * 72 + c8 * 8] = *(const uint4*)&qkvb[go];
    *(uint4*)&cs[row * 72 + c8 * 8] = *(const uint4*)&qkvb[go + CDIM];
  }
  __syncthreads();
  int dv0 = (t & 15) * 4, r0 = (t >> 4) * 4;
  float facc[4][4] = {};
  for (int dk = 0; dk < 64; ++dk) {
    f32x4 kvrow = *(const f32x4*)&kvs[dk * 64 + dv0];
    float a0 = bf2f(qs[(r0 + 0) * 72 + dk]);
    float a1 = bf2f(qs[(r0 + 1) * 72 + dk]);
    float a2 = bf2f(qs[(r0 + 2) * 72 + dk]);
    float a3 = bf2f(qs[(r0 + 3) * 72 + dk]);
    #pragma unroll
    for (int j = 0; j < 4; ++j) {
      facc[0][j] += a0 * kvrow[j];
      facc[1][j] += a1 * kvrow[j];
      facc[2][j] += a2 * kvrow[j];
      facc[3][j] += a3 * kvrow[j];
    }
  }
  #pragma unroll
  for (int i = 0; i < 4; ++i) {
    int row = r0 + i;
    u16 ov[4];
    #pragma unroll
    for (int j = 0; j < 4; ++j) {
      float qv = bf2f(qs[row * 72 + dv0 + j]);
      float cv = bf2f(cs[row * 72 + dv0 + j]);
      ov[j] = f2bf(0.125f * facc[i][j] + qv * cv);
    }
    uint2 uu;
    uu.x = (u32)ov[0] | ((u32)ov[1] << 16);
    uu.y = (u32)ov[2] | ((u32)ov[3] << 16);
    *(uint2*)&qkvb[(size_t)(b * NSEQ + n0 + row) * CQKV + h * HD + dv0] = uu;
  }
}

// ---------------- launch ----------------
extern "C" void kernel_launch(void* const* d_in, const int* in_sizes, int n_in,
                              void* d_out, int out_size, void* d_ws, size_t ws_size,
                              hipStream_t stream) {
  (void)in_sizes; (void)n_in; (void)out_size;
  const float* x      = (const float*)d_in[0];
  // d_in[1]=H, d_in[2]=W (56, hard-coded)
  const float* w_qkv  = (const float*)d_in[3];
  const float* w_proj = (const float*)d_in[4];
  const float* b_proj = (const float*)d_in[5];
  const float* w3 = (const float*)d_in[6];
  const float* b3 = (const float*)d_in[7];
  const float* w5 = (const float*)d_in[8];
  const float* b5 = (const float*)d_in[9];
  const float* w7 = (const float*)d_in[10];
  const float* b7 = (const float*)d_in[11];
  float* out = (float*)d_out;

  char* ws = (char*)d_ws;
  u16* qkvb = (u16*)ws;        ws += (size_t)50176 * 1536 * 2;   // 154.1 MB
  u16* wqb  = (u16*)ws;        ws += (size_t)1536 * 512 * 2;
  u16* wpb  = (u16*)ws;        ws += (size_t)512 * 512 * 2;
  float* maxb = (float*)ws;    ws += (size_t)16 * 512 * 4;
  float* sumb = (float*)ws;    ws += (size_t)16 * 512 * 4;
  float* kvpart = (float*)ws;  ws += (size_t)8 * 16 * 8 * 64 * 64 * 4;  // 16.8 MB
  float* kvb = (float*)ws;     ws += (size_t)16 * 8 * 64 * 64 * 4;      // 2.1 MB
  u16* xb = (u16*)ws;          ws += (size_t)50176 * 512 * 2;           // 51.4 MB (optional)
  bool use_xb = ((size_t)(ws - (char*)d_ws) <= ws_size);

  // colstats partials reuse kvpart scratch (dead until kv_partial runs)
  float* pm = kvpart;            // 1024*64 floats
  float* ps = kvpart + 65536;    // 1024*64 floats

  cvt_kernel<<<768, 256, 0, stream>>>(w_qkv, wqb, 1536 * 512 / 4);
  cvt_kernel<<<256, 256, 0, stream>>>(w_proj, wpb, 512 * 512 / 4);
  // qkv = x @ w_qkv^T  (bf16 MFMA); pre-convert x to bf16 if scratch allows
  if (use_xb) {
    cvt_kernel<<<25088, 256, 0, stream>>>(x, xb, 50176 * 512 / 4);
    gemm_bt<false, false><<<4704, 256, 0, stream>>>(xb, wqb, qkvb, nullptr,
                                                    50176, 1536, 512, 512, 512, 1536, 12);
  } else {
    gemm_bt<true, false><<<4704, 256, 0, stream>>>(x, wqb, qkvb, nullptr,
                                                   50176, 1536, 512, 512, 512, 1536, 12);
  }
  colstats_part_kernel<<<1024, 256, 0, stream>>>(qkvb, pm, ps);
  colstats_reduce_kernel<<<32, 256, 0, stream>>>(pm, ps, maxb, sumb);
  kv_partial_kernel<<<1024, 256, 0, stream>>>(qkvb, maxb, sumb, kvpart);
  kv_reduce_kernel<<<2048, 256, 0, stream>>>(kvpart, kvb);
  // depthwise convs: write conv_v over dead k region (cols 512:1024)
  conv_kernel<1><<<512, 256, 0, stream>>>(qkvb, w3, b3, 0, 2);
  conv_kernel<2><<<768, 256, 0, stream>>>(qkvb, w5, b5, 2, 3);
  conv_kernel<3><<<768, 256, 0, stream>>>(qkvb, w7, b7, 5, 3);
  // out_heads = SCALE*q@kv + q*conv_v  (in-place over q, cols 0:512)
  combine_kernel<<<6272, 256, 0, stream>>>(qkvb, kvb);
  // out = out_heads @ w_proj^T + b_proj  (fp32 out)
  gemm_bt<false, true><<<1568, 256, 0, stream>>>(qkvb, wpb, out, b_proj,
                                                 50176, 512, 512, 1536, 512, 512, 4);
}

// Round 4
// 369.324 us; speedup vs baseline: 1.7558x; 1.1095x over previous
//
#include <hip/hip_runtime.h>
#include <hip/hip_bf16.h>
#include <cstdint>
#include <cstddef>

using u16 = unsigned short;
using u32 = unsigned int;
using f32x4 = __attribute__((ext_vector_type(4))) float;
using bf16x8 = __attribute__((ext_vector_type(8))) short;

#define NB   16        // batch
#define NSEQ 3136      // 56*56
#define NH   8
#define HD   64
#define CDIM 512
#define CQKV 1536

static __device__ __forceinline__ u16 f2bf(float f) {
  u32 u = __builtin_bit_cast(u32, f);
  u = (u + 0x7FFFu + ((u >> 16) & 1u)) >> 16;
  return (u16)u;
}
static __device__ __forceinline__ float bf2f(u16 h) {
  u32 u = ((u32)h) << 16;
  return __builtin_bit_cast(float, u);
}
static __device__ __forceinline__ void async16(const void* g, void* l) {
  __builtin_amdgcn_global_load_lds((const __attribute__((address_space(1))) u32*)g,
                                   (__attribute__((address_space(3))) u32*)l, 16, 0, 0);
}

// ---------------- fp32 -> bf16 convert ----------------
__global__ __launch_bounds__(256) void cvt_kernel(const float* __restrict__ in,
                                                  u16* __restrict__ out, int n4) {
  int i = (int)(blockIdx.x * 256 + threadIdx.x);
  if (i >= n4) return;
  f32x4 v = *(const f32x4*)(in + (size_t)i * 4);
  uint2 uu;
  uu.x = (u32)f2bf(v[0]) | ((u32)f2bf(v[1]) << 16);
  uu.y = (u32)f2bf(v[2]) | ((u32)f2bf(v[3]) << 16);
  *(uint2*)(out + (size_t)i * 4) = uu;
}

// ================= 256x256 8-phase MFMA GEMM (T2+T3+T4+T5) =================
// C[m,n] = sum_k A[m,k]*B[n,k]. BM=BN=256, BK=64, 8 waves (2M x 4N), 512 thr.
// LDS 128 KiB: [buf2][A/B][half2][128*64] bf16, XOR-swizzled (row&7)<<3 elems.
// Staging: global_load_lds w16, linear LDS dest + inverse-swizzled source.
// Counted vmcnt ledger keeps >=2 half-tiles in flight across every barrier.
#define VMW(n) asm volatile("s_waitcnt vmcnt(" #n ")" ::: "memory")

template<bool OUT_FP32>
__global__ __launch_bounds__(512, 2) void gemm256(
    const u16* __restrict__ Ap, const u16* __restrict__ Bp, void* __restrict__ Cp,
    const float* __restrict__ bias, int K, int lda, int ldb, int ldc, int nbn)
{
  __shared__ u16 sm[2][2][2][128 * 64];
  int nwg = (int)gridDim.x;
  int bid = (int)blockIdx.x;
  int wg = (bid & 7) * (nwg >> 3) + (bid >> 3);   // XCD swizzle (nwg % 8 == 0)
  int bm = wg / nbn, bn = wg - bm * nbn;
  int m0 = bm * 256, n0 = bn * 256;
  int t = (int)threadIdx.x;
  int lane = t & 63, w = t >> 6;
  int wm = w >> 2, wn = w & 3;            // 2 x 4 waves
  int lr = lane & 15, lk = (lane >> 4) * 8;

  f32x4 acc[2][2][4][2] = {};             // [Mhalf][Nhalf][mi][ni]
  const int KT = K >> 6;

  // stage one half-tile (op: 0=A,1=B; half: 0/1) of K-tile kt into buffer b
  auto stage = [&](int b, int op, int half, int kt) {
    const u16* P = op ? Bp : Ap;
    int ld = op ? ldb : lda;
    int base0 = op ? n0 : m0;
    int gc = (kt << 6) + ((((t & 7) ^ ((t >> 3) & 7))) << 3);  // inverse-swizzled src col
    #pragma unroll
    for (int rd = 0; rd < 2; ++rd) {
      int gr = base0 + half * 128 + rd * 64 + (t >> 3);
      async16(P + (size_t)gr * ld + gc, &sm[b][op][half][rd * 4096 + w * 512]);
    }
  };
  auto lda_frag = [&](int b, int h, int mi, int kk) -> bf16x8 {
    int r = wm * 64 + mi * 16 + lr;
    int c = kk * 32 + lk;
    return *(const bf16x8*)&sm[b][0][h][r * 64 + (c ^ ((r & 7) << 3))];
  };
  auto ldb_frag = [&](int b, int g, int ni, int kk) -> bf16x8 {
    int r = wn * 32 + ni * 16 + lr;
    int c = kk * 32 + lk;
    return *(const bf16x8*)&sm[b][1][g][r * 64 + (c ^ ((r & 7) << 3))];
  };

#define GPH(bb_, h_, g_, STAGE_STMT, WAIT_STMT)                               \
  do {                                                                        \
    bf16x8 av[4][2], bv[2][2];                                                \
    _Pragma("unroll")                                                         \
    for (int mi = 0; mi < 4; ++mi) {                                          \
      _Pragma("unroll")                                                       \
      for (int kk = 0; kk < 2; ++kk) av[mi][kk] = lda_frag(bb_, h_, mi, kk);  \
    }                                                                         \
    _Pragma("unroll")                                                         \
    for (int ni = 0; ni < 2; ++ni) {                                          \
      _Pragma("unroll")                                                       \
      for (int kk = 0; kk < 2; ++kk) bv[ni][kk] = ldb_frag(bb_, g_, ni, kk);  \
    }                                                                         \
    STAGE_STMT;                                                               \
    WAIT_STMT;                                                                \
    __builtin_amdgcn_s_barrier();                                             \
    asm volatile("s_waitcnt lgkmcnt(0)" ::: "memory");                        \
    __builtin_amdgcn_sched_barrier(0);                                        \
    __builtin_amdgcn_s_setprio(1);                                            \
    _Pragma("unroll")                                                         \
    for (int kk = 0; kk < 2; ++kk) {                                          \
      _Pragma("unroll")                                                       \
      for (int mi = 0; mi < 4; ++mi) {                                        \
        _Pragma("unroll")                                                     \
        for (int ni = 0; ni < 2; ++ni)                                        \
          acc[h_][g_][mi][ni] = __builtin_amdgcn_mfma_f32_16x16x32_bf16(      \
              av[mi][kk], bv[ni][kk], acc[h_][g_][mi][ni], 0, 0, 0);          \
      }                                                                       \
    }                                                                         \
    __builtin_amdgcn_s_setprio(0);                                            \
    __builtin_amdgcn_s_barrier();                                             \
  } while (0)

  // prologue: stage K-tile 0 (A0,B0,A1,B1), wait for A0,B0
  stage(0, 0, 0, 0); stage(0, 1, 0, 0); stage(0, 0, 1, 0); stage(0, 1, 1, 0);
  VMW(4);
  __builtin_amdgcn_s_barrier();

  for (int kt = 0; kt < KT - 1; ++kt) {
    int bb = kt & 1;
    // phase order (Mhalf,Nhalf) matches staging arrival A0,B0,A1,B1
    GPH(bb, 0, 0, stage(bb ^ 1, 0, 0, kt + 1), VMW(4));  // next needs A1(kt)
    GPH(bb, 1, 0, stage(bb ^ 1, 1, 0, kt + 1), VMW(4));  // next needs B1(kt)
    GPH(bb, 1, 1, stage(bb ^ 1, 0, 1, kt + 1), (void)0); // next needs nothing
    GPH(bb, 0, 1, stage(bb ^ 1, 1, 1, kt + 1), VMW(4));  // next K-tile needs A0,B0
  }
  {
    int bb = (KT - 1) & 1;   // peeled last K-tile: no staging, drain 2->0
    GPH(bb, 0, 0, (void)0, VMW(2));
    GPH(bb, 1, 0, (void)0, VMW(0));
    GPH(bb, 1, 1, (void)0, (void)0);
    GPH(bb, 0, 1, (void)0, (void)0);
  }
#undef GPH

  // epilogue: C write
  #pragma unroll
  for (int h = 0; h < 2; ++h)
    #pragma unroll
    for (int g = 0; g < 2; ++g)
      #pragma unroll
      for (int mi = 0; mi < 4; ++mi)
        #pragma unroll
        for (int ni = 0; ni < 2; ++ni) {
          int gcol = n0 + g * 128 + wn * 32 + ni * 16 + lr;
          #pragma unroll
          for (int r = 0; r < 4; ++r) {
            int grow = m0 + h * 128 + wm * 64 + mi * 16 + (lane >> 4) * 4 + r;
            if constexpr (OUT_FP32) {
              ((float*)Cp)[(size_t)grow * ldc + gcol] = acc[h][g][mi][ni][r] + bias[gcol];
            } else {
              ((u16*)Cp)[(size_t)grow * ldc + gcol] = f2bf(acc[h][g][mi][ni][r]);
            }
          }
        }
}

// ---------------- legacy 128x128 GEMM (fallback when ws too small) ----------------
template<bool A_FP32, bool OUT_FP32>
__global__ __launch_bounds__(256) void gemm_bt(
    const void* __restrict__ Ap, const u16* __restrict__ Bp, void* __restrict__ Cp,
    const float* __restrict__ bias, int M, int N, int K, int lda, int ldb, int ldc, int nbn)
{
  __shared__ u16 As[128 * 64];
  __shared__ u16 Bs[128 * 64];
  int nwg = (int)gridDim.x;
  int bid = (int)blockIdx.x;
  int wg = (bid & 7) * (nwg >> 3) + (bid >> 3);
  int bm = wg / nbn, bn = wg - bm * nbn;
  int m0 = bm * 128, n0 = bn * 128;
  int t = (int)threadIdx.x;
  int lane = t & 63, w = t >> 6;
  int wm = w >> 1, wn = w & 1;
  f32x4 acc[4][4] = {};
  for (int k0 = 0; k0 < K; k0 += 64) {
    if constexpr (A_FP32) {
      const float* A = (const float*)Ap;
      #pragma unroll
      for (int i = 0; i < 8; ++i) {
        int e = i * 1024 + t * 4;
        int row = e >> 6, col = e & 63;
        f32x4 v = *(const f32x4*)(A + (size_t)(m0 + row) * lda + k0 + col);
        uint2 uu;
        uu.x = (u32)f2bf(v[0]) | ((u32)f2bf(v[1]) << 16);
        uu.y = (u32)f2bf(v[2]) | ((u32)f2bf(v[3]) << 16);
        *(uint2*)&As[row * 64 + col] = uu;
      }
    } else {
      const u16* A = (const u16*)Ap;
      #pragma unroll
      for (int i = 0; i < 4; ++i) {
        int chunk = w * 4 + i;
        int row = chunk * 8 + (lane >> 3);
        int col = (lane & 7) * 8;
        async16(A + (size_t)(m0 + row) * lda + k0 + col, &As[chunk * 512]);
      }
    }
    #pragma unroll
    for (int i = 0; i < 4; ++i) {
      int chunk = w * 4 + i;
      int row = chunk * 8 + (lane >> 3);
      int col = (lane & 7) * 8;
      async16(Bp + (size_t)(n0 + row) * ldb + k0 + col, &Bs[chunk * 512]);
    }
    __syncthreads();
    #pragma unroll
    for (int kk = 0; kk < 2; ++kk) {
      int lr = lane & 15;
      int lkk = kk * 32 + (lane >> 4) * 8;
      bf16x8 af[4], bq[4];
      #pragma unroll
      for (int mi = 0; mi < 4; ++mi)
        af[mi] = *(const bf16x8*)&As[(wm * 64 + mi * 16 + lr) * 64 + lkk];
      #pragma unroll
      for (int ni = 0; ni < 4; ++ni)
        bq[ni] = *(const bf16x8*)&Bs[(wn * 64 + ni * 16 + lr) * 64 + lkk];
      #pragma unroll
      for (int mi = 0; mi < 4; ++mi)
        #pragma unroll
        for (int ni = 0; ni < 4; ++ni)
          acc[mi][ni] = __builtin_amdgcn_mfma_f32_16x16x32_bf16(af[mi], bq[ni], acc[mi][ni], 0, 0, 0);
    }
    __syncthreads();
  }
  int lr = lane & 15, lg = lane >> 4;
  #pragma unroll
  for (int mi = 0; mi < 4; ++mi)
    #pragma unroll
    for (int ni = 0; ni < 4; ++ni) {
      int gcol = n0 + wn * 64 + ni * 16 + lr;
      #pragma unroll
      for (int r = 0; r < 4; ++r) {
        int grow = m0 + wm * 64 + mi * 16 + lg * 4 + r;
        if constexpr (OUT_FP32) {
          ((float*)Cp)[(size_t)grow * ldc + gcol] = acc[mi][ni][r] + bias[gcol];
        } else {
          ((u16*)Cp)[(size_t)grow * ldc + gcol] = f2bf(acc[mi][ni][r]);
        }
      }
    }
}

// ---------------- column softmax stats, pass 1: per (b,h,ns) chunk partials ----------------
__global__ __launch_bounds__(256) void colstats_part_kernel(const u16* __restrict__ qkvb,
                                                            float* __restrict__ pm,
                                                            float* __restrict__ ps) {
  int bid = (int)blockIdx.x;           // b*64 + h*8 + ns
  int ns = bid & 7, h = (bid >> 3) & 7, b = bid >> 6;
  int t = (int)threadIdx.x;
  int d8 = t & 7, rl = t >> 3;
  const u16* base = qkvb + (size_t)b * NSEQ * CQKV + CDIM + h * HD + d8 * 8;
  int nbase = ns * 392;
  float m[8], s[8];
  #pragma unroll
  for (int j = 0; j < 8; ++j) { m[j] = -3.0e38f; s[j] = 0.f; }
  for (int it = 0; it < 13; ++it) {
    int row = it * 32 + rl;
    if (row < 392) {
      uint4 val = *(const uint4*)(base + (size_t)(nbase + row) * CQKV);
      const u16* p = (const u16*)&val;
      #pragma unroll
      for (int j = 0; j < 8; ++j) {
        float v = bf2f(p[j]);
        if (v <= m[j]) { s[j] += __expf(v - m[j]); }
        else           { s[j] = s[j] * __expf(m[j] - v) + 1.f; m[j] = v; }
      }
    }
  }
  __shared__ float sm[256][8], ss[256][8];
  #pragma unroll
  for (int j = 0; j < 8; ++j) { sm[t][j] = m[j]; ss[t][j] = s[j]; }
  __syncthreads();
  if (t < 64) {
    int dd8 = t >> 3, dj = t & 7;
    float M = -3.0e38f, S = 0.f;
    #pragma unroll
    for (int r = 0; r < 32; ++r) {
      float m2 = sm[r * 8 + dd8][dj], s2 = ss[r * 8 + dd8][dj];
      if (m2 <= M) { S += s2 * __expf(m2 - M); }
      else         { S = S * __expf(M - m2) + s2; M = m2; }
    }
    pm[bid * 64 + t] = M;
    ps[bid * 64 + t] = S;
  }
}

// pass 2: combine 8 chunk partials per (b,h,d)
__global__ __launch_bounds__(256) void colstats_reduce_kernel(const float* __restrict__ pm,
                                                              const float* __restrict__ ps,
                                                              float* __restrict__ maxb,
                                                              float* __restrict__ sumb) {
  int idx = (int)(blockIdx.x * 256 + threadIdx.x);   // < 128*64
  int bh = idx >> 6, d = idx & 63;
  float M = -3.0e38f, S = 0.f;
  #pragma unroll
  for (int ns = 0; ns < 8; ++ns) {
    float m2 = pm[((bh << 3) + ns) * 64 + d], s2 = ps[((bh << 3) + ns) * 64 + d];
    if (m2 <= M) { S += s2 * __expf(m2 - M); }
    else         { S = S * __expf(M - m2) + s2; M = m2; }
  }
  maxb[idx] = M;
  sumb[idx] = S;
}

// ---------------- kv partials: kv[b,h,dk,dv] = sum_n softmax(k)[n,dk]*v[n,dv] ----------------
__global__ __launch_bounds__(256) void kv_partial_kernel(const u16* __restrict__ qkvb,
    const float* __restrict__ maxb, const float* __restrict__ sumb, float* __restrict__ part) {
  int bid = (int)blockIdx.x;
  int ns = bid & 7, h = (bid >> 3) & 7, b = bid >> 6;
  int t = (int)threadIdx.x;
  __shared__ float ek[56 * 64];
  __shared__ float vv[56 * 64];
  __shared__ float mx[64], ivs[64];
  if (t < 64) {
    mx[t]  = maxb[(b * 8 + h) * 64 + t];
    ivs[t] = 1.0f / sumb[(b * 8 + h) * 64 + t];
  }
  int dv0 = (t & 15) * 4, dk0 = (t >> 4) * 4;
  float acc[4][4] = {};
  int nbase = ns * 392;
  for (int c0 = 0; c0 < 392; c0 += 56) {
    __syncthreads();
    for (int idx = t; idx < 448; idx += 256) {
      int row = idx >> 3, c8 = idx & 7;
      size_t go = (size_t)(b * NSEQ + nbase + c0 + row) * CQKV + h * HD + c8 * 8;
      uint4 kq = *(const uint4*)&qkvb[go + CDIM];
      uint4 vq = *(const uint4*)&qkvb[go + 2 * CDIM];
      const u16* kp = (const u16*)&kq;
      const u16* vp = (const u16*)&vq;
      #pragma unroll
      for (int j = 0; j < 8; ++j) {
        int col = c8 * 8 + j;
        ek[row * 64 + col] = __expf(bf2f(kp[j]) - mx[col]) * ivs[col];
        vv[row * 64 + col] = bf2f(vp[j]);
      }
    }
    __syncthreads();
    for (int n = 0; n < 56; ++n) {
      f32x4 ekv = *(const f32x4*)&ek[n * 64 + dk0];
      f32x4 vvv = *(const f32x4*)&vv[n * 64 + dv0];
      #pragma unroll
      for (int i = 0; i < 4; ++i)
        #pragma unroll
        for (int j = 0; j < 4; ++j)
          acc[i][j] += ekv[i] * vvv[j];
    }
  }
  float* dst = part + (size_t)((ns * 16 + b) * 8 + h) * 4096;
  #pragma unroll
  for (int i = 0; i < 4; ++i) {
    f32x4 o;
    #pragma unroll
    for (int j = 0; j < 4; ++j) o[j] = acc[i][j];
    *(f32x4*)&dst[(dk0 + i) * 64 + dv0] = o;
  }
}

__global__ __launch_bounds__(256) void kv_reduce_kernel(const float* __restrict__ part,
                                                        float* __restrict__ kvb) {
  int idx = (int)(blockIdx.x * 256 + threadIdx.x);   // < 16*8*64*64
  float s = 0.f;
  #pragma unroll
  for (int ns = 0; ns < 8; ++ns) s += part[(size_t)ns * 524288 + idx];
  kvb[idx] = s;
}

// ---------------- depthwise conv on v (image layout), writes over dead k region ----------------
template<int R>
__global__ __launch_bounds__(256) void conv_kernel(u16* __restrict__ qkvb,
    const float* __restrict__ w, const float* __restrict__ bias, int hbase, int nh) {
  constexpr int KS = 2 * R + 1;
  constexpr int WT = 14 + 2 * R;
  __shared__ u16 vt[WT * WT * 64];
  int bid = (int)blockIdx.x;
  int hh = bid % nh;
  int tile = (bid / nh) & 15;
  int b = bid / (nh * 16);
  int h = hbase + hh;
  int y0 = (tile >> 2) * 14, x0 = (tile & 3) * 14;
  int t = (int)threadIdx.x;
  for (int idx = t; idx < WT * WT * 8; idx += 256) {
    int pix = idx >> 3, c8 = idx & 7;
    int py = pix / WT, px = pix - py * WT;
    int gy = y0 + py - R, gx = x0 + px - R;
    uint4 val; val.x = 0u; val.y = 0u; val.z = 0u; val.w = 0u;
    if (gy >= 0 && gy < 56 && gx >= 0 && gx < 56)
      val = *(const uint4*)&qkvb[(size_t)(b * NSEQ + gy * 56 + gx) * CQKV + 2 * CDIM + h * HD + c8 * 8];
    *(uint4*)&vt[pix * 64 + c8 * 8] = val;
  }
  __syncthreads();
  int d = t & 63, g = t >> 6;
  int cg = hh * 64 + d;
  float wr[KS * KS];
  #pragma unroll
  for (int i = 0; i < KS * KS; ++i) wr[i] = w[cg * KS * KS + i];
  float bb = bias[cg];
  for (int px = g; px < 14; px += 4) {
    float acc[14];
    #pragma unroll
    for (int i = 0; i < 14; ++i) acc[i] = bb;
    #pragma unroll
    for (int iy = 0; iy < 14 + 2 * R; ++iy) {
      float val[KS];
      #pragma unroll
      for (int dx = 0; dx < KS; ++dx) val[dx] = bf2f(vt[(iy * WT + px + dx) * 64 + d]);
      #pragma unroll
      for (int dy = 0; dy < KS; ++dy) {
        int py = iy - dy;
        if (py >= 0 && py < 14) {
          #pragma unroll
          for (int dx = 0; dx < KS; ++dx) acc[py] += wr[dy * KS + dx] * val[dx];
        }
      }
    }
    #pragma unroll
    for (int py = 0; py < 14; ++py)
      qkvb[(size_t)(b * NSEQ + (y0 + py) * 56 + x0 + px) * CQKV + CDIM + h * HD + d] = f2bf(acc[py]);
  }
}

// ---------------- combine: out_heads = SCALE * q@kv + q*conv_v, in-place over q ----------------
__global__ __launch_bounds__(256) void combine_kernel(u16* __restrict__ qkvb,
                                                      const float* __restrict__ kvb) {
  int bid = (int)blockIdx.x;
  int rt = bid % 49;
  int h = (bid / 49) & 7;
  int b = bid / 392;
  int n0 = rt * 64;
  int t = (int)threadIdx.x;
  __shared__ float kvs[64 * 64];
  __shared__ u16 qs[64 * 72];
  __shared__ u16 cs[64 * 72];
  const float* src = kvb + (size_t)(b * 8 + h) * 4096;
  #pragma unroll
  for (int i = 0; i < 16; ++i) kvs[i * 256 + t] = src[i * 256 + t];
  #pragma unroll
  for (int i = 0; i < 2; ++i) {
    int chunk = i * 256 + t;
    int row = chunk >> 3, c8 = chunk & 7;
    size_t go = (size_t)(b * NSEQ + n0 + row) * CQKV + h * HD + c8 * 8;
    *(uint4*)&qs[row * 72 + c8 * 8] = *(const uint4*)&qkvb[go];
    *(uint4*)&cs[row * 72 + c8 * 8] = *(const uint4*)&qkvb[go + CDIM];
  }
  __syncthreads();
  int dv0 = (t & 15) * 4, r0 = (t >> 4) * 4;
  float facc[4][4] = {};
  #pragma unroll
  for (int c8 = 0; c8 < 8; ++c8) {     // dk chunks of 8: vectorized LDS reads
    bf16x8 qv[4];
    #pragma unroll
    for (int i = 0; i < 4; ++i) qv[i] = *(const bf16x8*)&qs[(r0 + i) * 72 + c8 * 8];
    #pragma unroll
    for (int j = 0; j < 8; ++j) {
      f32x4 kvr = *(const f32x4*)&kvs[(c8 * 8 + j) * 64 + dv0];
      #pragma unroll
      for (int i = 0; i < 4; ++i) {
        float a = bf2f((u16)qv[i][j]);
        #pragma unroll
        for (int jj = 0; jj < 4; ++jj) facc[i][jj] += a * kvr[jj];
      }
    }
  }
  #pragma unroll
  for (int i = 0; i < 4; ++i) {
    int row = r0 + i;
    u16 ov[4];
    #pragma unroll
    for (int j = 0; j < 4; ++j) {
      float qv = bf2f(qs[row * 72 + dv0 + j]);
      float cv = bf2f(cs[row * 72 + dv0 + j]);
      ov[j] = f2bf(0.125f * facc[i][j] + qv * cv);
    }
    uint2 uu;
    uu.x = (u32)ov[0] | ((u32)ov[1] << 16);
    uu.y = (u32)ov[2] | ((u32)ov[3] << 16);
    *(uint2*)&qkvb[(size_t)(b * NSEQ + n0 + row) * CQKV + h * HD + dv0] = uu;
  }
}

// ---------------- launch ----------------
extern "C" void kernel_launch(void* const* d_in, const int* in_sizes, int n_in,
                              void* d_out, int out_size, void* d_ws, size_t ws_size,
                              hipStream_t stream) {
  (void)in_sizes; (void)n_in; (void)out_size;
  const float* x      = (const float*)d_in[0];
  // d_in[1]=H, d_in[2]=W (56, hard-coded)
  const float* w_qkv  = (const float*)d_in[3];
  const float* w_proj = (const float*)d_in[4];
  const float* b_proj = (const float*)d_in[5];
  const float* w3 = (const float*)d_in[6];
  const float* b3 = (const float*)d_in[7];
  const float* w5 = (const float*)d_in[8];
  const float* b5 = (const float*)d_in[9];
  const float* w7 = (const float*)d_in[10];
  const float* b7 = (const float*)d_in[11];
  float* out = (float*)d_out;

  char* ws = (char*)d_ws;
  u16* qkvb = (u16*)ws;        ws += (size_t)50176 * 1536 * 2;   // 154.1 MB
  u16* wqb  = (u16*)ws;        ws += (size_t)1536 * 512 * 2;
  u16* wpb  = (u16*)ws;        ws += (size_t)512 * 512 * 2;
  float* maxb = (float*)ws;    ws += (size_t)16 * 512 * 4;
  float* sumb = (float*)ws;    ws += (size_t)16 * 512 * 4;
  float* kvpart = (float*)ws;  ws += (size_t)8 * 16 * 8 * 64 * 64 * 4;  // 16.8 MB
  float* kvb = (float*)ws;     ws += (size_t)16 * 8 * 64 * 64 * 4;      // 2.1 MB
  u16* xb = (u16*)ws;          ws += (size_t)50176 * 512 * 2;           // 51.4 MB (optional)
  bool use_xb = ((size_t)(ws - (char*)d_ws) <= ws_size);

  // colstats partials reuse kvpart scratch (dead until kv_partial runs)
  float* pm = kvpart;            // 1024*64 floats
  float* ps = kvpart + 65536;    // 1024*64 floats

  cvt_kernel<<<768, 256, 0, stream>>>(w_qkv, wqb, 1536 * 512 / 4);
  cvt_kernel<<<256, 256, 0, stream>>>(w_proj, wpb, 512 * 512 / 4);
  // qkv = x @ w_qkv^T  (bf16 MFMA, 256^2 8-phase)
  if (use_xb) {
    cvt_kernel<<<25088, 256, 0, stream>>>(x, xb, 50176 * 512 / 4);
    gemm256<false><<<1176, 512, 0, stream>>>(xb, wqb, qkvb, nullptr,
                                             512, 512, 512, 1536, 6);
  } else {
    gemm_bt<true, false><<<4704, 256, 0, stream>>>(x, wqb, qkvb, nullptr,
                                                   50176, 1536, 512, 512, 512, 1536, 12);
  }
  colstats_part_kernel<<<1024, 256, 0, stream>>>(qkvb, pm, ps);
  colstats_reduce_kernel<<<32, 256, 0, stream>>>(pm, ps, maxb, sumb);
  kv_partial_kernel<<<1024, 256, 0, stream>>>(qkvb, maxb, sumb, kvpart);
  kv_reduce_kernel<<<2048, 256, 0, stream>>>(kvpart, kvb);
  // depthwise convs: write conv_v over dead k region (cols 512:1024)
  conv_kernel<1><<<512, 256, 0, stream>>>(qkvb, w3, b3, 0, 2);
  conv_kernel<2><<<768, 256, 0, stream>>>(qkvb, w5, b5, 2, 3);
  conv_kernel<3><<<768, 256, 0, stream>>>(qkvb, w7, b7, 5, 3);
  // out_heads = SCALE*q@kv + q*conv_v  (in-place over q, cols 0:512)
  combine_kernel<<<6272, 256, 0, stream>>>(qkvb, kvb);
  // out = out_heads @ w_proj^T + b_proj  (fp32 out, 256^2 8-phase)
  if (use_xb) {
    gemm256<true><<<392, 512, 0, stream>>>(qkvb, wpb, out, b_proj,
                                           512, 1536, 512, 512, 2);
  } else {
    gemm_bt<false, true><<<1568, 256, 0, stream>>>(qkvb, wpb, out, b_proj,
                                                   50176, 512, 512, 1536, 512, 512, 4);
  }
}